// Round 1
// baseline (1489.455 us; speedup 1.0000x reference)
//
#include <hip/hip_runtime.h>
#include <math.h>

#define NF 128   // feature width (both in and out of every layer)

// ---------------------------------------------------------------------------
// Precompute kernels: degree count, dinv + CSR offset allocation, CSR fill
// ---------------------------------------------------------------------------
__global__ __launch_bounds__(256) void k_count(const int* __restrict__ col,
                                               int* __restrict__ cnt, int E) {
  int i = blockIdx.x * blockDim.x + threadIdx.x;
  if (i < E) atomicAdd(&cnt[col[i]], 1);
}

__global__ __launch_bounds__(256) void k_nodeinit(const int* __restrict__ cnt,
                                                  float* __restrict__ dinv,
                                                  int* __restrict__ offs,
                                                  int* __restrict__ cursor,
                                                  int* __restrict__ total, int N) {
  int i = blockIdx.x * blockDim.x + threadIdx.x;
  if (i < N) {
    int c = cnt[i];
    // deg = (#incoming edges) + FILL(2.0) from the self-loop; always > 0
    dinv[i] = rsqrtf((float)c + 2.0f);
    int o = atomicAdd(total, c);   // segment placement order is irrelevant (sum)
    offs[i] = o;
    cursor[i] = o;
  }
}

__global__ __launch_bounds__(256) void k_fill(const int* __restrict__ row,
                                              const int* __restrict__ col,
                                              const float* __restrict__ dinv,
                                              int* __restrict__ cursor,
                                              int2* __restrict__ csr, int E) {
  int i = blockIdx.x * blockDim.x + threadIdx.x;
  if (i < E) {
    int r = row[i], c = col[i];
    int p = atomicAdd(&cursor[c], 1);
    csr[p] = make_int2(r, __float_as_int(dinv[r] * dinv[c]));
  }
}

// ---------------------------------------------------------------------------
// GEMM: out[N,128] = H[N,128] @ W[128,128]  (f32 vector FMA; W + H-tile in LDS)
// Per block: 32 rows/tile, 256 threads, each thread 4 rows x 4 cols.
// ---------------------------------------------------------------------------
__global__ __launch_bounds__(256) void k_gemm(const float* __restrict__ H,
                                              const float* __restrict__ W,
                                              float* __restrict__ out, int nRows) {
  __shared__ float Wl[128][128];   // 64 KiB
  __shared__ float Hl[32][128];    // 16 KiB

  // Load W into LDS (once per block)
  for (int i = threadIdx.x; i < 128 * 128 / 4; i += 256) {
    reinterpret_cast<float4*>(&Wl[0][0])[i] = reinterpret_cast<const float4*>(W)[i];
  }

  const int c4 = (threadIdx.x & 31) * 4;       // output col base (0..124)
  const int rg = (threadIdx.x >> 5) * 4;       // row-group base within tile (0..28)

  int nTiles = (nRows + 31) / 32;
  for (int tile = blockIdx.x; tile < nTiles; tile += gridDim.x) {
    int rowBase = tile * 32;
    __syncthreads();   // protect Hl (prev iter readers) / cover W load on iter 0
    for (int i = threadIdx.x; i < 32 * 128 / 4; i += 256) {
      int r = i >> 5;          // 32 float4 per row
      int gr = rowBase + r;
      float4 v = make_float4(0.f, 0.f, 0.f, 0.f);
      if (gr < nRows) v = reinterpret_cast<const float4*>(H + (size_t)gr * NF)[i & 31];
      reinterpret_cast<float4*>(&Hl[0][0])[i] = v;
    }
    __syncthreads();

    float acc[4][4];
#pragma unroll
    for (int j = 0; j < 4; ++j)
#pragma unroll
      for (int c = 0; c < 4; ++c) acc[j][c] = 0.f;

#pragma unroll 4
    for (int k = 0; k < 128; ++k) {
      float4 w = *reinterpret_cast<float4*>(&Wl[k][c4]);
      float hv[4];
#pragma unroll
      for (int j = 0; j < 4; ++j) hv[j] = Hl[rg + j][k];
#pragma unroll
      for (int j = 0; j < 4; ++j) {
        acc[j][0] = fmaf(hv[j], w.x, acc[j][0]);
        acc[j][1] = fmaf(hv[j], w.y, acc[j][1]);
        acc[j][2] = fmaf(hv[j], w.z, acc[j][2]);
        acc[j][3] = fmaf(hv[j], w.w, acc[j][3]);
      }
    }

#pragma unroll
    for (int j = 0; j < 4; ++j) {
      int gr = rowBase + rg + j;
      if (gr < nRows) {
        float4 v = make_float4(acc[j][0], acc[j][1], acc[j][2], acc[j][3]);
        *reinterpret_cast<float4*>(out + (size_t)gr * NF + c4) = v;
      }
    }
  }
}

// ---------------------------------------------------------------------------
// Aggregation: h[v] = tanh( sum_{e:col=v} tmp[src_e]*w_e + 2*dinv[v]^2*tmp[v] + b )
// One wave per node; lane handles 2 features (float2).
// ---------------------------------------------------------------------------
__global__ __launch_bounds__(256) void k_agg(const float* __restrict__ tmp,
                                             const int* __restrict__ offs,
                                             const int* __restrict__ ends,
                                             const int2* __restrict__ csr,
                                             const float* __restrict__ dinv,
                                             const float* __restrict__ bias,
                                             float* __restrict__ hout, int N) {
  int node = blockIdx.x * 4 + (threadIdx.x >> 6);
  if (node >= N) return;
  int lane = threadIdx.x & 63;

  float di = dinv[node];
  float selfw = 2.0f * di * di;

  const float2* trow = reinterpret_cast<const float2*>(tmp + (size_t)node * NF);
  float2 hv = trow[lane];
  float2 acc;
  acc.x = selfw * hv.x;
  acc.y = selfw * hv.y;

  int s = offs[node], e = ends[node];
  for (int i = s; i < e; ++i) {
    int2 ed = csr[i];                       // (src, w bits) — wave-uniform load
    float w = __int_as_float(ed.y);
    float2 hv2 = reinterpret_cast<const float2*>(tmp + (size_t)ed.x * NF)[lane];
    acc.x = fmaf(w, hv2.x, acc.x);
    acc.y = fmaf(w, hv2.y, acc.y);
  }

  float2 b2 = reinterpret_cast<const float2*>(bias)[lane];
  float2 r;
  r.x = tanhf(acc.x + b2.x);
  r.y = tanhf(acc.y + b2.y);
  reinterpret_cast<float2*>(hout + (size_t)node * NF)[lane] = r;
}

// ---------------------------------------------------------------------------
// Pool (segment max + mean over sorted batch_index) fused with the linear head.
// One block (128 threads) per graph.
// ---------------------------------------------------------------------------
__global__ __launch_bounds__(128) void k_pool(const float* __restrict__ h,
                                              const int* __restrict__ batch,
                                              const float* __restrict__ Wout,
                                              const float* __restrict__ bout,
                                              float* __restrict__ out, int N) {
  int g = blockIdx.x;

  // lower_bound(batch, g) and lower_bound(batch, g+1): all threads redundantly
  int lo = 0, hi = N;
  while (lo < hi) { int mid = (lo + hi) >> 1; if (batch[mid] < g) lo = mid + 1; else hi = mid; }
  int s = lo;
  int lo2 = s, hi2 = N;
  while (lo2 < hi2) { int mid = (lo2 + hi2) >> 1; if (batch[mid] < g + 1) lo2 = mid + 1; else hi2 = mid; }
  int e = lo2;

  int f = threadIdx.x;
  float mx = -INFINITY, sm = 0.f;
  int n = s;
  for (; n + 1 < e; n += 2) {          // 2-way unroll for load overlap
    float v0 = h[(size_t)n * NF + f];
    float v1 = h[(size_t)(n + 1) * NF + f];
    mx = fmaxf(mx, fmaxf(v0, v1));
    sm += v0 + v1;
  }
  if (n < e) {
    float v0 = h[(size_t)n * NF + f];
    mx = fmaxf(mx, v0);
    sm += v0;
  }

  int cnt = e - s;
  float mean = sm / fmaxf((float)cnt, 1.0f);
  if (cnt == 0) mx = 0.f;

  float part = mx * Wout[f] + mean * Wout[NF + f];

  // reduce 128 threads = 2 waves
  for (int o = 32; o > 0; o >>= 1) part += __shfl_down(part, o);
  __shared__ float wsum[2];
  if ((threadIdx.x & 63) == 0) wsum[threadIdx.x >> 6] = part;
  __syncthreads();
  if (threadIdx.x == 0) out[g] = wsum[0] + wsum[1] + bout[0];
}

// ---------------------------------------------------------------------------
// Driver
// ---------------------------------------------------------------------------
extern "C" void kernel_launch(void* const* d_in, const int* in_sizes, int n_in,
                              void* d_out, int out_size, void* d_ws, size_t ws_size,
                              hipStream_t stream) {
  const float* x     = (const float*)d_in[0];
  const int*   eidx  = (const int*)d_in[1];     // [2][E]
  const int*   batch = (const int*)d_in[2];     // [N]
  const float* W0    = (const float*)d_in[3];
  const float* b0    = (const float*)d_in[4];
  const float* Whid  = (const float*)d_in[5];   // [2][128][128]
  const float* bhid  = (const float*)d_in[6];   // [2][128]
  const float* Wout  = (const float*)d_in[7];   // [256]
  const float* bout  = (const float*)d_in[8];   // [1]
  float* out = (float*)d_out;

  const int N = in_sizes[0] / NF;
  const int E = in_sizes[1] / 2;
  const int G = out_size;

  const int* erow = eidx;
  const int* ecol = eidx + E;

  // workspace layout (256B aligned)
  size_t off = 0;
  auto alloc = [&](size_t bytes) -> void* {
    void* p = (char*)d_ws + off;
    off += (bytes + 255) & ~(size_t)255;
    return p;
  };
  int*   cnt    = (int*)alloc((size_t)N * 4);
  float* dinv   = (float*)alloc((size_t)N * 4);
  int*   offs   = (int*)alloc((size_t)N * 4);
  int*   cursor = (int*)alloc((size_t)N * 4);
  int*   total  = (int*)alloc(16);
  int2*  csr    = (int2*)alloc((size_t)E * 8);
  float* tmp    = (float*)alloc((size_t)N * NF * 4);
  float* h      = (float*)alloc((size_t)N * NF * 4);
  (void)ws_size;

  hipMemsetAsync(cnt, 0, (size_t)N * 4, stream);
  hipMemsetAsync(total, 0, 16, stream);

  int gE = (E + 255) / 256;
  int gN = (N + 255) / 256;

  k_count<<<gE, 256, 0, stream>>>(ecol, cnt, E);
  k_nodeinit<<<gN, 256, 0, stream>>>(cnt, dinv, offs, cursor, total, N);
  k_fill<<<gE, 256, 0, stream>>>(erow, ecol, dinv, cursor, csr, E);

  const int gemmGrid = 1024;
  const int aggGrid = (N + 3) / 4;

  // layer 0: x -> tmp -> h
  k_gemm<<<gemmGrid, 256, 0, stream>>>(x, W0, tmp, N);
  k_agg<<<aggGrid, 256, 0, stream>>>(tmp, offs, cursor, csr, dinv, b0, h, N);
  // layer 1
  k_gemm<<<gemmGrid, 256, 0, stream>>>(h, Whid, tmp, N);
  k_agg<<<aggGrid, 256, 0, stream>>>(tmp, offs, cursor, csr, dinv, bhid, h, N);
  // layer 2
  k_gemm<<<gemmGrid, 256, 0, stream>>>(h, Whid + 128 * 128, tmp, N);
  k_agg<<<aggGrid, 256, 0, stream>>>(tmp, offs, cursor, csr, dinv, bhid + NF, h, N);

  // pooling + head
  k_pool<<<G, 128, 0, stream>>>(h, batch, Wout, bout, out, N);
}

// Round 2
// 1184.584 us; speedup vs baseline: 1.2574x; 1.2574x over previous
//
#include <hip/hip_runtime.h>
#include <math.h>

#define NF 128   // feature width (both in and out of every layer)

// ---------------------------------------------------------------------------
// Precompute kernels: degree count, dinv + CSR offset allocation, CSR fill
// ---------------------------------------------------------------------------
__global__ __launch_bounds__(256) void k_count(const int* __restrict__ col,
                                               int* __restrict__ cnt, int E) {
  int i = blockIdx.x * blockDim.x + threadIdx.x;
  if (i < E) atomicAdd(&cnt[col[i]], 1);
}

__global__ __launch_bounds__(256) void k_nodeinit(const int* __restrict__ cnt,
                                                  float* __restrict__ dinv,
                                                  int* __restrict__ offs,
                                                  int* __restrict__ cursor,
                                                  int* __restrict__ total, int N) {
  int i = blockIdx.x * blockDim.x + threadIdx.x;
  if (i < N) {
    int c = cnt[i];
    // deg = (#incoming edges) + FILL(2.0) from the self-loop; always > 0
    dinv[i] = rsqrtf((float)c + 2.0f);
    int o = atomicAdd(total, c);   // segment placement order is irrelevant (sum)
    offs[i] = o;
    cursor[i] = o;
  }
}

__global__ __launch_bounds__(256) void k_fill(const int* __restrict__ row,
                                              const int* __restrict__ col,
                                              const float* __restrict__ dinv,
                                              int* __restrict__ cursor,
                                              int2* __restrict__ csr, int E) {
  int i = blockIdx.x * blockDim.x + threadIdx.x;
  if (i < E) {
    int r = row[i], c = col[i];
    int p = atomicAdd(&cursor[c], 1);
    csr[p] = make_int2(r, __float_as_int(dinv[r] * dinv[c]));
  }
}

// ---------------------------------------------------------------------------
// GEMM: out[N,128] = H[N,128] @ W[128,128]  (f32 vector FMA)
// Tile 64 rows x 128 cols per block, BK=32 K-chunks.
// 256 threads; thread = 8 rows x 4 cols. LDS 25 KB -> ~6 blocks/CU.
// ---------------------------------------------------------------------------
#define BM 64
#define BK 32
__global__ __launch_bounds__(256) void k_gemm(const float* __restrict__ H,
                                              const float* __restrict__ W,
                                              float* __restrict__ out, int nRows) {
  __shared__ float Wl[BK][NF];       // 16 KB
  __shared__ float Hl[BM][BK + 4];   // stride 36 floats (144 B, 16B-aligned), 9 KB

  const int tid = threadIdx.x;
  const int c4 = (tid & 31) * 4;     // output col base
  const int rg = (tid >> 5) * 8;     // row-group base (8 rows per thread)
  const int rowBase = blockIdx.x * BM;

  float acc[8][4];
#pragma unroll
  for (int j = 0; j < 8; ++j)
#pragma unroll
    for (int c = 0; c < 4; ++c) acc[j][c] = 0.f;

  for (int kc = 0; kc < NF; kc += BK) {
    __syncthreads();   // protect LDS from previous chunk's readers
    // stage W chunk [BK][128] (contiguous copy)
    {
      const float4* src = reinterpret_cast<const float4*>(W + (size_t)kc * NF);
      float4* dst = reinterpret_cast<float4*>(&Wl[0][0]);
      for (int i = tid; i < BK * NF / 4; i += 256) dst[i] = src[i];
    }
    // stage H chunk [BM][BK]
    {
      int r0 = tid >> 3;
      int cs = (tid & 7) * 4;
#pragma unroll
      for (int half = 0; half < 2; ++half) {
        int r = r0 + half * 32;
        int gr = rowBase + r;
        float4 v = make_float4(0.f, 0.f, 0.f, 0.f);
        if (gr < nRows)
          v = *reinterpret_cast<const float4*>(H + (size_t)gr * NF + kc + cs);
        *reinterpret_cast<float4*>(&Hl[r][cs]) = v;
      }
    }
    __syncthreads();

#pragma unroll
    for (int k = 0; k < BK; k += 4) {
      float4 w0 = *reinterpret_cast<float4*>(&Wl[k + 0][c4]);
      float4 w1 = *reinterpret_cast<float4*>(&Wl[k + 1][c4]);
      float4 w2 = *reinterpret_cast<float4*>(&Wl[k + 2][c4]);
      float4 w3 = *reinterpret_cast<float4*>(&Wl[k + 3][c4]);
#pragma unroll
      for (int j = 0; j < 8; ++j) {
        float4 hv = *reinterpret_cast<float4*>(&Hl[rg + j][k]);   // broadcast read
        acc[j][0] = fmaf(hv.x, w0.x, acc[j][0]);
        acc[j][1] = fmaf(hv.x, w0.y, acc[j][1]);
        acc[j][2] = fmaf(hv.x, w0.z, acc[j][2]);
        acc[j][3] = fmaf(hv.x, w0.w, acc[j][3]);
        acc[j][0] = fmaf(hv.y, w1.x, acc[j][0]);
        acc[j][1] = fmaf(hv.y, w1.y, acc[j][1]);
        acc[j][2] = fmaf(hv.y, w1.z, acc[j][2]);
        acc[j][3] = fmaf(hv.y, w1.w, acc[j][3]);
        acc[j][0] = fmaf(hv.z, w2.x, acc[j][0]);
        acc[j][1] = fmaf(hv.z, w2.y, acc[j][1]);
        acc[j][2] = fmaf(hv.z, w2.z, acc[j][2]);
        acc[j][3] = fmaf(hv.z, w2.w, acc[j][3]);
        acc[j][0] = fmaf(hv.w, w3.x, acc[j][0]);
        acc[j][1] = fmaf(hv.w, w3.y, acc[j][1]);
        acc[j][2] = fmaf(hv.w, w3.z, acc[j][2]);
        acc[j][3] = fmaf(hv.w, w3.w, acc[j][3]);
      }
    }
  }

#pragma unroll
  for (int j = 0; j < 8; ++j) {
    int gr = rowBase + rg + j;
    if (gr < nRows) {
      float4 v = make_float4(acc[j][0], acc[j][1], acc[j][2], acc[j][3]);
      *reinterpret_cast<float4*>(out + (size_t)gr * NF + c4) = v;
    }
  }
}

// ---------------------------------------------------------------------------
// Aggregation: h[v] = tanh( sum_{e:col=v} tmp[src_e]*w_e + 2*dinv[v]^2*tmp[v] + b )
// Half-wave (32 lanes) per node, float4 per lane (512 B row per load instr).
// Edge loop unrolled x4 -> ~8 gathers in flight per wave.
// ---------------------------------------------------------------------------
__global__ __launch_bounds__(256) void k_agg(const float* __restrict__ tmp,
                                             const int* __restrict__ offs,
                                             const int* __restrict__ ends,
                                             const int2* __restrict__ csr,
                                             const float* __restrict__ dinv,
                                             const float* __restrict__ bias,
                                             float* __restrict__ hout, int N) {
  int node = (blockIdx.x * 256 + threadIdx.x) >> 5;
  if (node >= N) return;
  int lane = threadIdx.x & 31;

  float di = dinv[node];
  float selfw = 2.0f * di * di;

  const float4* t4 = reinterpret_cast<const float4*>(tmp);
  float4 hv = t4[(size_t)node * 32 + lane];
  float4 acc = make_float4(selfw * hv.x, selfw * hv.y, selfw * hv.z, selfw * hv.w);

  int s = offs[node], e = ends[node];
  int i = s;
  for (; i + 4 <= e; i += 4) {
    int2 e0 = csr[i];
    int2 e1 = csr[i + 1];
    int2 e2 = csr[i + 2];
    int2 e3 = csr[i + 3];
    float4 a = t4[(size_t)e0.x * 32 + lane];
    float4 b = t4[(size_t)e1.x * 32 + lane];
    float4 c = t4[(size_t)e2.x * 32 + lane];
    float4 d = t4[(size_t)e3.x * 32 + lane];
    float w0 = __int_as_float(e0.y), w1 = __int_as_float(e1.y);
    float w2 = __int_as_float(e2.y), w3 = __int_as_float(e3.y);
    acc.x = fmaf(w0, a.x, acc.x); acc.y = fmaf(w0, a.y, acc.y);
    acc.z = fmaf(w0, a.z, acc.z); acc.w = fmaf(w0, a.w, acc.w);
    acc.x = fmaf(w1, b.x, acc.x); acc.y = fmaf(w1, b.y, acc.y);
    acc.z = fmaf(w1, b.z, acc.z); acc.w = fmaf(w1, b.w, acc.w);
    acc.x = fmaf(w2, c.x, acc.x); acc.y = fmaf(w2, c.y, acc.y);
    acc.z = fmaf(w2, c.z, acc.z); acc.w = fmaf(w2, c.w, acc.w);
    acc.x = fmaf(w3, d.x, acc.x); acc.y = fmaf(w3, d.y, acc.y);
    acc.z = fmaf(w3, d.z, acc.z); acc.w = fmaf(w3, d.w, acc.w);
  }
  for (; i < e; ++i) {
    int2 ee = csr[i];
    float4 a = t4[(size_t)ee.x * 32 + lane];
    float w = __int_as_float(ee.y);
    acc.x = fmaf(w, a.x, acc.x); acc.y = fmaf(w, a.y, acc.y);
    acc.z = fmaf(w, a.z, acc.z); acc.w = fmaf(w, a.w, acc.w);
  }

  float4 b4 = reinterpret_cast<const float4*>(bias)[lane];
  float4 r;
  r.x = tanhf(acc.x + b4.x);
  r.y = tanhf(acc.y + b4.y);
  r.z = tanhf(acc.z + b4.z);
  r.w = tanhf(acc.w + b4.w);
  reinterpret_cast<float4*>(hout)[(size_t)node * 32 + lane] = r;
}

// ---------------------------------------------------------------------------
// Pool (segment max + mean over sorted batch_index) fused with the linear head.
// One block (512 threads = 4 row-stripes of 128 features) per graph.
// ---------------------------------------------------------------------------
__global__ __launch_bounds__(512) void k_pool(const float* __restrict__ h,
                                              const int* __restrict__ batch,
                                              const float* __restrict__ Wout,
                                              const float* __restrict__ bout,
                                              float* __restrict__ out, int N) {
  int g = blockIdx.x;

  // lower_bound(batch, g) and lower_bound(batch, g+1): all threads redundantly
  int lo = 0, hi = N;
  while (lo < hi) { int mid = (lo + hi) >> 1; if (batch[mid] < g) lo = mid + 1; else hi = mid; }
  int s = lo;
  int lo2 = s, hi2 = N;
  while (lo2 < hi2) { int mid = (lo2 + hi2) >> 1; if (batch[mid] < g + 1) lo2 = mid + 1; else hi2 = mid; }
  int e = lo2;

  int f = threadIdx.x & 127;
  int stripe = threadIdx.x >> 7;   // 0..3

  float mx = -INFINITY, sm = 0.f;
  for (int n = s + stripe; n < e; n += 4) {
    float v = h[(size_t)n * NF + f];
    mx = fmaxf(mx, v);
    sm += v;
  }

  __shared__ float smx[4][NF];
  __shared__ float ssm[4][NF];
  smx[stripe][f] = mx;
  ssm[stripe][f] = sm;
  __syncthreads();

  if (stripe == 0) {
    mx = fmaxf(fmaxf(smx[0][f], smx[1][f]), fmaxf(smx[2][f], smx[3][f]));
    sm = ssm[0][f] + ssm[1][f] + ssm[2][f] + ssm[3][f];

    int cnt = e - s;
    float mean = sm / fmaxf((float)cnt, 1.0f);
    if (cnt == 0) mx = 0.f;

    float part = mx * Wout[f] + mean * Wout[NF + f];

    // reduce 128 threads = 2 waves
    for (int o = 32; o > 0; o >>= 1) part += __shfl_down(part, o);
    __shared__ float wsum[2];
    if ((threadIdx.x & 63) == 0) wsum[threadIdx.x >> 6] = part;
    __syncthreads();
    if (threadIdx.x == 0) out[g] = wsum[0] + wsum[1] + bout[0];
  }
}

// ---------------------------------------------------------------------------
// Driver
// ---------------------------------------------------------------------------
extern "C" void kernel_launch(void* const* d_in, const int* in_sizes, int n_in,
                              void* d_out, int out_size, void* d_ws, size_t ws_size,
                              hipStream_t stream) {
  const float* x     = (const float*)d_in[0];
  const int*   eidx  = (const int*)d_in[1];     // [2][E]
  const int*   batch = (const int*)d_in[2];     // [N]
  const float* W0    = (const float*)d_in[3];
  const float* b0    = (const float*)d_in[4];
  const float* Whid  = (const float*)d_in[5];   // [2][128][128]
  const float* bhid  = (const float*)d_in[6];   // [2][128]
  const float* Wout  = (const float*)d_in[7];   // [256]
  const float* bout  = (const float*)d_in[8];   // [1]
  float* out = (float*)d_out;

  const int N = in_sizes[0] / NF;
  const int E = in_sizes[1] / 2;
  const int G = out_size;

  const int* erow = eidx;
  const int* ecol = eidx + E;

  // workspace layout (256B aligned)
  size_t off = 0;
  auto alloc = [&](size_t bytes) -> void* {
    void* p = (char*)d_ws + off;
    off += (bytes + 255) & ~(size_t)255;
    return p;
  };
  int*   cnt    = (int*)alloc((size_t)N * 4);
  float* dinv   = (float*)alloc((size_t)N * 4);
  int*   offs   = (int*)alloc((size_t)N * 4);
  int*   cursor = (int*)alloc((size_t)N * 4);
  int*   total  = (int*)alloc(16);
  int2*  csr    = (int2*)alloc((size_t)E * 8);
  float* tmp    = (float*)alloc((size_t)N * NF * 4);
  float* h      = (float*)alloc((size_t)N * NF * 4);
  (void)ws_size;

  hipMemsetAsync(cnt, 0, (size_t)N * 4, stream);
  hipMemsetAsync(total, 0, 16, stream);

  int gE = (E + 255) / 256;
  int gN = (N + 255) / 256;

  k_count<<<gE, 256, 0, stream>>>(ecol, cnt, E);
  k_nodeinit<<<gN, 256, 0, stream>>>(cnt, dinv, offs, cursor, total, N);
  k_fill<<<gE, 256, 0, stream>>>(erow, ecol, dinv, cursor, csr, E);

  const int gemmGrid = (N + BM - 1) / BM;
  const int aggGrid = (N + 7) / 8;          // 8 nodes (half-waves) per 256-thr block

  // layer 0: x -> tmp -> h
  k_gemm<<<gemmGrid, 256, 0, stream>>>(x, W0, tmp, N);
  k_agg<<<aggGrid, 256, 0, stream>>>(tmp, offs, cursor, csr, dinv, b0, h, N);
  // layer 1
  k_gemm<<<gemmGrid, 256, 0, stream>>>(h, Whid, tmp, N);
  k_agg<<<aggGrid, 256, 0, stream>>>(tmp, offs, cursor, csr, dinv, bhid, h, N);
  // layer 2
  k_gemm<<<gemmGrid, 256, 0, stream>>>(h, Whid + 128 * 128, tmp, N);
  k_agg<<<aggGrid, 256, 0, stream>>>(tmp, offs, cursor, csr, dinv, bhid + NF, h, N);

  // pooling + head
  k_pool<<<G, 512, 0, stream>>>(h, batch, Wout, bout, out, N);
}

// Round 4
// 1175.250 us; speedup vs baseline: 1.2674x; 1.0079x over previous
//
#include <hip/hip_runtime.h>
#include <math.h>

#define NF 128   // feature width (both in and out of every layer)

typedef int  vint4  __attribute__((ext_vector_type(4)));
typedef float vfloat4 __attribute__((ext_vector_type(4)));

// ---------------------------------------------------------------------------
// Precompute kernels: degree count, dinv + CSR offset allocation, CSR fill
// ---------------------------------------------------------------------------
__global__ __launch_bounds__(256) void k_count(const int* __restrict__ col,
                                               int* __restrict__ cnt, int E) {
  int i = blockIdx.x * blockDim.x + threadIdx.x;
  if (i < E) atomicAdd(&cnt[col[i]], 1);
}

__global__ __launch_bounds__(256) void k_nodeinit(const int* __restrict__ cnt,
                                                  float* __restrict__ dinv,
                                                  int* __restrict__ offs,
                                                  int* __restrict__ cursor,
                                                  int* __restrict__ total, int N) {
  int i = blockIdx.x * blockDim.x + threadIdx.x;
  if (i < N) {
    int c = cnt[i];
    // deg = (#incoming edges) + FILL(2.0) from the self-loop; always > 0
    dinv[i] = rsqrtf((float)c + 2.0f);
    int o = atomicAdd(total, c);   // segment placement order is irrelevant (sum)
    offs[i] = o;
    cursor[i] = o;
  }
}

__global__ __launch_bounds__(256) void k_fill(const int* __restrict__ row,
                                              const int* __restrict__ col,
                                              const float* __restrict__ dinv,
                                              int* __restrict__ cursor,
                                              int2* __restrict__ csr, int E) {
  int i = blockIdx.x * blockDim.x + threadIdx.x;
  if (i < E) {
    int r = row[i], c = col[i];
    int p = atomicAdd(&cursor[c], 1);
    csr[p] = make_int2(r, __float_as_int(dinv[r] * dinv[c]));
  }
}

// ---------------------------------------------------------------------------
// GEMM: out[N,128] = H[N,128] @ W[128,128]  (f32 vector FMA)
// Tile 64 rows x 128 cols per block, BK=32 K-chunks.
// 256 threads; thread = 8 rows x 4 cols. LDS 25 KB -> ~6 blocks/CU.
// ---------------------------------------------------------------------------
#define BM 64
#define BK 32
__global__ __launch_bounds__(256) void k_gemm(const float* __restrict__ H,
                                              const float* __restrict__ W,
                                              float* __restrict__ out, int nRows) {
  __shared__ float Wl[BK][NF];       // 16 KB
  __shared__ float Hl[BM][BK + 4];   // stride 36 floats (144 B, 16B-aligned), 9 KB

  const int tid = threadIdx.x;
  const int c4 = (tid & 31) * 4;     // output col base
  const int rg = (tid >> 5) * 8;     // row-group base (8 rows per thread)
  const int rowBase = blockIdx.x * BM;

  float acc[8][4];
#pragma unroll
  for (int j = 0; j < 8; ++j)
#pragma unroll
    for (int c = 0; c < 4; ++c) acc[j][c] = 0.f;

  for (int kc = 0; kc < NF; kc += BK) {
    __syncthreads();   // protect LDS from previous chunk's readers
    // stage W chunk [BK][128] (contiguous copy)
    {
      const float4* src = reinterpret_cast<const float4*>(W + (size_t)kc * NF);
      float4* dst = reinterpret_cast<float4*>(&Wl[0][0]);
      for (int i = tid; i < BK * NF / 4; i += 256) dst[i] = src[i];
    }
    // stage H chunk [BM][BK]
    {
      int r0 = tid >> 3;
      int cs = (tid & 7) * 4;
#pragma unroll
      for (int half = 0; half < 2; ++half) {
        int r = r0 + half * 32;
        int gr = rowBase + r;
        float4 v = make_float4(0.f, 0.f, 0.f, 0.f);
        if (gr < nRows)
          v = *reinterpret_cast<const float4*>(H + (size_t)gr * NF + kc + cs);
        *reinterpret_cast<float4*>(&Hl[r][cs]) = v;
      }
    }
    __syncthreads();

#pragma unroll
    for (int k = 0; k < BK; k += 4) {
      float4 w0 = *reinterpret_cast<float4*>(&Wl[k + 0][c4]);
      float4 w1 = *reinterpret_cast<float4*>(&Wl[k + 1][c4]);
      float4 w2 = *reinterpret_cast<float4*>(&Wl[k + 2][c4]);
      float4 w3 = *reinterpret_cast<float4*>(&Wl[k + 3][c4]);
#pragma unroll
      for (int j = 0; j < 8; ++j) {
        float4 hv = *reinterpret_cast<float4*>(&Hl[rg + j][k]);   // broadcast read
        acc[j][0] = fmaf(hv.x, w0.x, acc[j][0]);
        acc[j][1] = fmaf(hv.x, w0.y, acc[j][1]);
        acc[j][2] = fmaf(hv.x, w0.z, acc[j][2]);
        acc[j][3] = fmaf(hv.x, w0.w, acc[j][3]);
        acc[j][0] = fmaf(hv.y, w1.x, acc[j][0]);
        acc[j][1] = fmaf(hv.y, w1.y, acc[j][1]);
        acc[j][2] = fmaf(hv.y, w1.z, acc[j][2]);
        acc[j][3] = fmaf(hv.y, w1.w, acc[j][3]);
        acc[j][0] = fmaf(hv.z, w2.x, acc[j][0]);
        acc[j][1] = fmaf(hv.z, w2.y, acc[j][1]);
        acc[j][2] = fmaf(hv.z, w2.z, acc[j][2]);
        acc[j][3] = fmaf(hv.z, w2.w, acc[j][3]);
        acc[j][0] = fmaf(hv.w, w3.x, acc[j][0]);
        acc[j][1] = fmaf(hv.w, w3.y, acc[j][1]);
        acc[j][2] = fmaf(hv.w, w3.z, acc[j][2]);
        acc[j][3] = fmaf(hv.w, w3.w, acc[j][3]);
      }
    }
  }

#pragma unroll
  for (int j = 0; j < 8; ++j) {
    int gr = rowBase + rg + j;
    if (gr < nRows) {
      float4 v = make_float4(acc[j][0], acc[j][1], acc[j][2], acc[j][3]);
      *reinterpret_cast<float4*>(out + (size_t)gr * NF + c4) = v;
    }
  }
}

// ---------------------------------------------------------------------------
// Aggregation: h[v] = tanh( sum_{e:col=v} tmp[src_e]*w_e + 2*dinv[v]^2*tmp[v] + b )
// Half-wave (32 lanes) per node, float4 per lane (512 B row per load instr).
// Edge loop unrolled x8, CSR read as 2-edge int4 (nontemporal: csr is
// streamed once per layer; keep L2 for the tmp gathers). Result stored
// nontemporally (hout only re-read sequentially by the next GEMM).
// ---------------------------------------------------------------------------
__device__ __forceinline__ float4 fma4(float w, float4 a, float4 acc) {
  acc.x = fmaf(w, a.x, acc.x);
  acc.y = fmaf(w, a.y, acc.y);
  acc.z = fmaf(w, a.z, acc.z);
  acc.w = fmaf(w, a.w, acc.w);
  return acc;
}

__global__ __launch_bounds__(256) void k_agg(const float* __restrict__ tmp,
                                             const int* __restrict__ offs,
                                             const int* __restrict__ ends,
                                             const int2* __restrict__ csr,
                                             const float* __restrict__ dinv,
                                             const float* __restrict__ bias,
                                             float* __restrict__ hout, int N) {
  int node = (blockIdx.x * 256 + threadIdx.x) >> 5;
  if (node >= N) return;
  int lane = threadIdx.x & 31;

  float di = dinv[node];
  float selfw = 2.0f * di * di;

  const float4* t4 = reinterpret_cast<const float4*>(tmp);
  float4 hv = t4[(size_t)node * 32 + lane];
  float4 acc = make_float4(selfw * hv.x, selfw * hv.y, selfw * hv.z, selfw * hv.w);

  int s = offs[node], e = ends[node];
  int i = s;

  // align i to even so vint4 (2-edge) loads are 16B-aligned
  if ((i & 1) && i < e) {
    int2 ee = csr[i];
    float4 a = t4[(size_t)ee.x * 32 + lane];
    acc = fma4(__int_as_float(ee.y), a, acc);
    ++i;
  }

  const vint4* cp = reinterpret_cast<const vint4*>(csr);
  for (; i + 8 <= e; i += 8) {
    vint4 p0 = __builtin_nontemporal_load(&cp[(i >> 1) + 0]);
    vint4 p1 = __builtin_nontemporal_load(&cp[(i >> 1) + 1]);
    vint4 p2 = __builtin_nontemporal_load(&cp[(i >> 1) + 2]);
    vint4 p3 = __builtin_nontemporal_load(&cp[(i >> 1) + 3]);
    float4 a0 = t4[(size_t)p0.x * 32 + lane];
    float4 a1 = t4[(size_t)p0.z * 32 + lane];
    float4 a2 = t4[(size_t)p1.x * 32 + lane];
    float4 a3 = t4[(size_t)p1.z * 32 + lane];
    float4 a4 = t4[(size_t)p2.x * 32 + lane];
    float4 a5 = t4[(size_t)p2.z * 32 + lane];
    float4 a6 = t4[(size_t)p3.x * 32 + lane];
    float4 a7 = t4[(size_t)p3.z * 32 + lane];
    acc = fma4(__int_as_float(p0.y), a0, acc);
    acc = fma4(__int_as_float(p0.w), a1, acc);
    acc = fma4(__int_as_float(p1.y), a2, acc);
    acc = fma4(__int_as_float(p1.w), a3, acc);
    acc = fma4(__int_as_float(p2.y), a4, acc);
    acc = fma4(__int_as_float(p2.w), a5, acc);
    acc = fma4(__int_as_float(p3.y), a6, acc);
    acc = fma4(__int_as_float(p3.w), a7, acc);
  }
  for (; i + 2 <= e; i += 2) {
    vint4 p = __builtin_nontemporal_load(&cp[i >> 1]);
    float4 a0 = t4[(size_t)p.x * 32 + lane];
    float4 a1 = t4[(size_t)p.z * 32 + lane];
    acc = fma4(__int_as_float(p.y), a0, acc);
    acc = fma4(__int_as_float(p.w), a1, acc);
  }
  if (i < e) {
    int2 ee = csr[i];
    float4 a = t4[(size_t)ee.x * 32 + lane];
    acc = fma4(__int_as_float(ee.y), a, acc);
  }

  float4 b4 = reinterpret_cast<const float4*>(bias)[lane];
  vfloat4 r;
  r.x = tanhf(acc.x + b4.x);
  r.y = tanhf(acc.y + b4.y);
  r.z = tanhf(acc.z + b4.z);
  r.w = tanhf(acc.w + b4.w);
  vfloat4* outp = reinterpret_cast<vfloat4*>(hout) + ((size_t)node * 32 + lane);
  __builtin_nontemporal_store(r, outp);
}

// ---------------------------------------------------------------------------
// Pool (segment max + mean over sorted batch_index) fused with the linear head.
// One block (512 threads = 4 row-stripes of 128 features) per graph.
// ---------------------------------------------------------------------------
__global__ __launch_bounds__(512) void k_pool(const float* __restrict__ h,
                                              const int* __restrict__ batch,
                                              const float* __restrict__ Wout,
                                              const float* __restrict__ bout,
                                              float* __restrict__ out, int N) {
  int g = blockIdx.x;

  // lower_bound(batch, g) and lower_bound(batch, g+1): all threads redundantly
  int lo = 0, hi = N;
  while (lo < hi) { int mid = (lo + hi) >> 1; if (batch[mid] < g) lo = mid + 1; else hi = mid; }
  int s = lo;
  int lo2 = s, hi2 = N;
  while (lo2 < hi2) { int mid = (lo2 + hi2) >> 1; if (batch[mid] < g + 1) lo2 = mid + 1; else hi2 = mid; }
  int e = lo2;

  int f = threadIdx.x & 127;
  int stripe = threadIdx.x >> 7;   // 0..3

  float mx = -INFINITY, sm = 0.f;
  for (int n = s + stripe; n < e; n += 4) {
    float v = h[(size_t)n * NF + f];
    mx = fmaxf(mx, v);
    sm += v;
  }

  __shared__ float smx[4][NF];
  __shared__ float ssm[4][NF];
  smx[stripe][f] = mx;
  ssm[stripe][f] = sm;
  __syncthreads();

  if (stripe == 0) {
    mx = fmaxf(fmaxf(smx[0][f], smx[1][f]), fmaxf(smx[2][f], smx[3][f]));
    sm = ssm[0][f] + ssm[1][f] + ssm[2][f] + ssm[3][f];

    int cnt = e - s;
    float mean = sm / fmaxf((float)cnt, 1.0f);
    if (cnt == 0) mx = 0.f;

    float part = mx * Wout[f] + mean * Wout[NF + f];

    // reduce 128 threads = 2 waves
    for (int o = 32; o > 0; o >>= 1) part += __shfl_down(part, o);
    __shared__ float wsum[2];
    if ((threadIdx.x & 63) == 0) wsum[threadIdx.x >> 6] = part;
    __syncthreads();
    if (threadIdx.x == 0) out[g] = wsum[0] + wsum[1] + bout[0];
  }
}

// ---------------------------------------------------------------------------
// Driver
// ---------------------------------------------------------------------------
extern "C" void kernel_launch(void* const* d_in, const int* in_sizes, int n_in,
                              void* d_out, int out_size, void* d_ws, size_t ws_size,
                              hipStream_t stream) {
  const float* x     = (const float*)d_in[0];
  const int*   eidx  = (const int*)d_in[1];     // [2][E]
  const int*   batch = (const int*)d_in[2];     // [N]
  const float* W0    = (const float*)d_in[3];
  const float* b0    = (const float*)d_in[4];
  const float* Whid  = (const float*)d_in[5];   // [2][128][128]
  const float* bhid  = (const float*)d_in[6];   // [2][128]
  const float* Wout  = (const float*)d_in[7];   // [256]
  const float* bout  = (const float*)d_in[8];   // [1]
  float* out = (float*)d_out;

  const int N = in_sizes[0] / NF;
  const int E = in_sizes[1] / 2;
  const int G = out_size;

  const int* erow = eidx;
  const int* ecol = eidx + E;

  // workspace layout (256B aligned)
  size_t off = 0;
  auto alloc = [&](size_t bytes) -> void* {
    void* p = (char*)d_ws + off;
    off += (bytes + 255) & ~(size_t)255;
    return p;
  };
  int*   cnt    = (int*)alloc((size_t)N * 4);
  float* dinv   = (float*)alloc((size_t)N * 4);
  int*   offs   = (int*)alloc((size_t)N * 4);
  int*   cursor = (int*)alloc((size_t)N * 4);
  int*   total  = (int*)alloc(16);
  int2*  csr    = (int2*)alloc((size_t)E * 8);
  float* tmp    = (float*)alloc((size_t)N * NF * 4);
  float* h      = (float*)alloc((size_t)N * NF * 4);
  (void)ws_size;

  (void)hipMemsetAsync(cnt, 0, (size_t)N * 4, stream);
  (void)hipMemsetAsync(total, 0, 16, stream);

  int gE = (E + 255) / 256;
  int gN = (N + 255) / 256;

  k_count<<<gE, 256, 0, stream>>>(ecol, cnt, E);
  k_nodeinit<<<gN, 256, 0, stream>>>(cnt, dinv, offs, cursor, total, N);
  k_fill<<<gE, 256, 0, stream>>>(erow, ecol, dinv, cursor, csr, E);

  const int gemmGrid = (N + BM - 1) / BM;
  const int aggGrid = (N + 7) / 8;          // 8 nodes (half-waves) per 256-thr block

  // layer 0: x -> tmp -> h
  k_gemm<<<gemmGrid, 256, 0, stream>>>(x, W0, tmp, N);
  k_agg<<<aggGrid, 256, 0, stream>>>(tmp, offs, cursor, csr, dinv, b0, h, N);
  // layer 1
  k_gemm<<<gemmGrid, 256, 0, stream>>>(h, Whid, tmp, N);
  k_agg<<<aggGrid, 256, 0, stream>>>(tmp, offs, cursor, csr, dinv, bhid, h, N);
  // layer 2
  k_gemm<<<gemmGrid, 256, 0, stream>>>(h, Whid + 128 * 128, tmp, N);
  k_agg<<<aggGrid, 256, 0, stream>>>(tmp, offs, cursor, csr, dinv, bhid + NF, h, N);

  // pooling + head
  k_pool<<<G, 512, 0, stream>>>(h, batch, Wout, bout, out, N);
}

// Round 5
// 885.599 us; speedup vs baseline: 1.6819x; 1.3271x over previous
//
#include <hip/hip_runtime.h>
#include <math.h>

#define NF 128   // feature width (both in and out of every layer)

typedef int      vint4  __attribute__((ext_vector_type(4)));
typedef float    vfloat4 __attribute__((ext_vector_type(4)));
typedef _Float16 vhalf4 __attribute__((ext_vector_type(4)));

// ---------------------------------------------------------------------------
// Precompute kernels: degree count, dinv + CSR offset allocation, CSR fill
// ---------------------------------------------------------------------------
__global__ __launch_bounds__(256) void k_count(const int* __restrict__ col,
                                               int* __restrict__ cnt, int E) {
  int i = blockIdx.x * blockDim.x + threadIdx.x;
  if (i < E) atomicAdd(&cnt[col[i]], 1);
}

__global__ __launch_bounds__(256) void k_nodeinit(const int* __restrict__ cnt,
                                                  float* __restrict__ dinv,
                                                  int* __restrict__ offs,
                                                  int* __restrict__ cursor,
                                                  int* __restrict__ total, int N) {
  int i = blockIdx.x * blockDim.x + threadIdx.x;
  if (i < N) {
    int c = cnt[i];
    // deg = (#incoming edges) + FILL(2.0) from the self-loop; always > 0
    dinv[i] = rsqrtf((float)c + 2.0f);
    int o = atomicAdd(total, c);   // segment placement order is irrelevant (sum)
    offs[i] = o;
    cursor[i] = o;
  }
}

__global__ __launch_bounds__(256) void k_fill(const int* __restrict__ row,
                                              const int* __restrict__ col,
                                              const float* __restrict__ dinv,
                                              int* __restrict__ cursor,
                                              int2* __restrict__ csr, int E) {
  int i = blockIdx.x * blockDim.x + threadIdx.x;
  if (i < E) {
    int r = row[i], c = col[i];
    int p = atomicAdd(&cursor[c], 1);
    csr[p] = make_int2(r, __float_as_int(dinv[r] * dinv[c]));
  }
}

// ---------------------------------------------------------------------------
// GEMM: out[N,128] = H[N,128] @ W[128,128]  (f32 vector FMA, fp16 output)
// Tile 64 rows x 128 cols per block, BK=32 K-chunks.
// 256 threads; thread = 8 rows x 4 cols.
// ---------------------------------------------------------------------------
#define BM 64
#define BK 32
__global__ __launch_bounds__(256) void k_gemm(const float* __restrict__ H,
                                              const float* __restrict__ W,
                                              _Float16* __restrict__ out, int nRows) {
  __shared__ float Wl[BK][NF];       // 16 KB
  __shared__ float Hl[BM][BK + 4];   // stride 36 floats (144 B, 16B-aligned), 9 KB

  const int tid = threadIdx.x;
  const int c4 = (tid & 31) * 4;     // output col base
  const int rg = (tid >> 5) * 8;     // row-group base (8 rows per thread)
  const int rowBase = blockIdx.x * BM;

  float acc[8][4];
#pragma unroll
  for (int j = 0; j < 8; ++j)
#pragma unroll
    for (int c = 0; c < 4; ++c) acc[j][c] = 0.f;

  for (int kc = 0; kc < NF; kc += BK) {
    __syncthreads();   // protect LDS from previous chunk's readers
    // stage W chunk [BK][128] (contiguous copy)
    {
      const float4* src = reinterpret_cast<const float4*>(W + (size_t)kc * NF);
      float4* dst = reinterpret_cast<float4*>(&Wl[0][0]);
      for (int i = tid; i < BK * NF / 4; i += 256) dst[i] = src[i];
    }
    // stage H chunk [BM][BK]
    {
      int r0 = tid >> 3;
      int cs = (tid & 7) * 4;
#pragma unroll
      for (int half = 0; half < 2; ++half) {
        int r = r0 + half * 32;
        int gr = rowBase + r;
        float4 v = make_float4(0.f, 0.f, 0.f, 0.f);
        if (gr < nRows)
          v = *reinterpret_cast<const float4*>(H + (size_t)gr * NF + kc + cs);
        *reinterpret_cast<float4*>(&Hl[r][cs]) = v;
      }
    }
    __syncthreads();

#pragma unroll
    for (int k = 0; k < BK; k += 4) {
      float4 w0 = *reinterpret_cast<float4*>(&Wl[k + 0][c4]);
      float4 w1 = *reinterpret_cast<float4*>(&Wl[k + 1][c4]);
      float4 w2 = *reinterpret_cast<float4*>(&Wl[k + 2][c4]);
      float4 w3 = *reinterpret_cast<float4*>(&Wl[k + 3][c4]);
#pragma unroll
      for (int j = 0; j < 8; ++j) {
        float4 hv = *reinterpret_cast<float4*>(&Hl[rg + j][k]);   // broadcast read
        acc[j][0] = fmaf(hv.x, w0.x, acc[j][0]);
        acc[j][1] = fmaf(hv.x, w0.y, acc[j][1]);
        acc[j][2] = fmaf(hv.x, w0.z, acc[j][2]);
        acc[j][3] = fmaf(hv.x, w0.w, acc[j][3]);
        acc[j][0] = fmaf(hv.y, w1.x, acc[j][0]);
        acc[j][1] = fmaf(hv.y, w1.y, acc[j][1]);
        acc[j][2] = fmaf(hv.y, w1.z, acc[j][2]);
        acc[j][3] = fmaf(hv.y, w1.w, acc[j][3]);
        acc[j][0] = fmaf(hv.z, w2.x, acc[j][0]);
        acc[j][1] = fmaf(hv.z, w2.y, acc[j][1]);
        acc[j][2] = fmaf(hv.z, w2.z, acc[j][2]);
        acc[j][3] = fmaf(hv.z, w2.w, acc[j][3]);
        acc[j][0] = fmaf(hv.w, w3.x, acc[j][0]);
        acc[j][1] = fmaf(hv.w, w3.y, acc[j][1]);
        acc[j][2] = fmaf(hv.w, w3.z, acc[j][2]);
        acc[j][3] = fmaf(hv.w, w3.w, acc[j][3]);
      }
    }
  }

#pragma unroll
  for (int j = 0; j < 8; ++j) {
    int gr = rowBase + rg + j;
    if (gr < nRows) {
      vhalf4 v;
      v.x = (_Float16)acc[j][0];
      v.y = (_Float16)acc[j][1];
      v.z = (_Float16)acc[j][2];
      v.w = (_Float16)acc[j][3];
      *reinterpret_cast<vhalf4*>(out + (size_t)gr * NF + c4) = v;
    }
  }
}

// ---------------------------------------------------------------------------
// Aggregation: h[v] = tanh( sum_{e:col=v} tmp[src_e]*w_e + 2*dinv[v]^2*tmp[v] + b )
// tmp is fp16 (halves random-gather bytes + footprint; f32 accumulation).
// Half-wave (32 lanes) per node, half4 (8 B) per lane = 256 B/row per instr.
// Edge loop unrolled x8, CSR read as 2-edge int4 nontemporal.
// ---------------------------------------------------------------------------
__device__ __forceinline__ float4 h2f(vhalf4 v) {
  return make_float4((float)v.x, (float)v.y, (float)v.z, (float)v.w);
}
__device__ __forceinline__ float4 fma4(float w, float4 a, float4 acc) {
  acc.x = fmaf(w, a.x, acc.x);
  acc.y = fmaf(w, a.y, acc.y);
  acc.z = fmaf(w, a.z, acc.z);
  acc.w = fmaf(w, a.w, acc.w);
  return acc;
}

__global__ __launch_bounds__(256) void k_agg(const _Float16* __restrict__ tmp,
                                             const int* __restrict__ offs,
                                             const int* __restrict__ ends,
                                             const int2* __restrict__ csr,
                                             const float* __restrict__ dinv,
                                             const float* __restrict__ bias,
                                             float* __restrict__ hout, int N) {
  int node = (blockIdx.x * 256 + threadIdx.x) >> 5;
  if (node >= N) return;
  int lane = threadIdx.x & 31;

  float di = dinv[node];
  float selfw = 2.0f * di * di;

  const vhalf4* t4 = reinterpret_cast<const vhalf4*>(tmp);
  float4 hv = h2f(t4[(size_t)node * 32 + lane]);
  float4 acc = make_float4(selfw * hv.x, selfw * hv.y, selfw * hv.z, selfw * hv.w);

  int s = offs[node], e = ends[node];
  int i = s;

  // align i to even so vint4 (2-edge) loads are 16B-aligned
  if ((i & 1) && i < e) {
    int2 ee = csr[i];
    float4 a = h2f(t4[(size_t)ee.x * 32 + lane]);
    acc = fma4(__int_as_float(ee.y), a, acc);
    ++i;
  }

  const vint4* cp = reinterpret_cast<const vint4*>(csr);
  for (; i + 8 <= e; i += 8) {
    vint4 p0 = __builtin_nontemporal_load(&cp[(i >> 1) + 0]);
    vint4 p1 = __builtin_nontemporal_load(&cp[(i >> 1) + 1]);
    vint4 p2 = __builtin_nontemporal_load(&cp[(i >> 1) + 2]);
    vint4 p3 = __builtin_nontemporal_load(&cp[(i >> 1) + 3]);
    float4 a0 = h2f(t4[(size_t)p0.x * 32 + lane]);
    float4 a1 = h2f(t4[(size_t)p0.z * 32 + lane]);
    float4 a2 = h2f(t4[(size_t)p1.x * 32 + lane]);
    float4 a3 = h2f(t4[(size_t)p1.z * 32 + lane]);
    float4 a4 = h2f(t4[(size_t)p2.x * 32 + lane]);
    float4 a5 = h2f(t4[(size_t)p2.z * 32 + lane]);
    float4 a6 = h2f(t4[(size_t)p3.x * 32 + lane]);
    float4 a7 = h2f(t4[(size_t)p3.z * 32 + lane]);
    acc = fma4(__int_as_float(p0.y), a0, acc);
    acc = fma4(__int_as_float(p0.w), a1, acc);
    acc = fma4(__int_as_float(p1.y), a2, acc);
    acc = fma4(__int_as_float(p1.w), a3, acc);
    acc = fma4(__int_as_float(p2.y), a4, acc);
    acc = fma4(__int_as_float(p2.w), a5, acc);
    acc = fma4(__int_as_float(p3.y), a6, acc);
    acc = fma4(__int_as_float(p3.w), a7, acc);
  }
  for (; i + 2 <= e; i += 2) {
    vint4 p = __builtin_nontemporal_load(&cp[i >> 1]);
    float4 a0 = h2f(t4[(size_t)p.x * 32 + lane]);
    float4 a1 = h2f(t4[(size_t)p.z * 32 + lane]);
    acc = fma4(__int_as_float(p.y), a0, acc);
    acc = fma4(__int_as_float(p.w), a1, acc);
  }
  if (i < e) {
    int2 ee = csr[i];
    float4 a = h2f(t4[(size_t)ee.x * 32 + lane]);
    acc = fma4(__int_as_float(ee.y), a, acc);
  }

  float4 b4 = reinterpret_cast<const float4*>(bias)[lane];
  vfloat4 r;
  r.x = tanhf(acc.x + b4.x);
  r.y = tanhf(acc.y + b4.y);
  r.z = tanhf(acc.z + b4.z);
  r.w = tanhf(acc.w + b4.w);
  vfloat4* outp = reinterpret_cast<vfloat4*>(hout) + ((size_t)node * 32 + lane);
  __builtin_nontemporal_store(r, outp);
}

// ---------------------------------------------------------------------------
// Pool (segment max + mean over sorted batch_index) fused with the linear head.
// One block (512 threads = 4 row-stripes of 128 features) per graph.
// ---------------------------------------------------------------------------
__global__ __launch_bounds__(512) void k_pool(const float* __restrict__ h,
                                              const int* __restrict__ batch,
                                              const float* __restrict__ Wout,
                                              const float* __restrict__ bout,
                                              float* __restrict__ out, int N) {
  int g = blockIdx.x;

  // lower_bound(batch, g) and lower_bound(batch, g+1): all threads redundantly
  int lo = 0, hi = N;
  while (lo < hi) { int mid = (lo + hi) >> 1; if (batch[mid] < g) lo = mid + 1; else hi = mid; }
  int s = lo;
  int lo2 = s, hi2 = N;
  while (lo2 < hi2) { int mid = (lo2 + hi2) >> 1; if (batch[mid] < g + 1) lo2 = mid + 1; else hi2 = mid; }
  int e = lo2;

  int f = threadIdx.x & 127;
  int stripe = threadIdx.x >> 7;   // 0..3

  float mx = -INFINITY, sm = 0.f;
  for (int n = s + stripe; n < e; n += 4) {
    float v = h[(size_t)n * NF + f];
    mx = fmaxf(mx, v);
    sm += v;
  }

  __shared__ float smx[4][NF];
  __shared__ float ssm[4][NF];
  smx[stripe][f] = mx;
  ssm[stripe][f] = sm;
  __syncthreads();

  if (stripe == 0) {
    mx = fmaxf(fmaxf(smx[0][f], smx[1][f]), fmaxf(smx[2][f], smx[3][f]));
    sm = ssm[0][f] + ssm[1][f] + ssm[2][f] + ssm[3][f];

    int cnt = e - s;
    float mean = sm / fmaxf((float)cnt, 1.0f);
    if (cnt == 0) mx = 0.f;

    float part = mx * Wout[f] + mean * Wout[NF + f];

    // reduce 128 threads = 2 waves
    for (int o = 32; o > 0; o >>= 1) part += __shfl_down(part, o);
    __shared__ float wsum[2];
    if ((threadIdx.x & 63) == 0) wsum[threadIdx.x >> 6] = part;
    __syncthreads();
    if (threadIdx.x == 0) out[g] = wsum[0] + wsum[1] + bout[0];
  }
}

// ---------------------------------------------------------------------------
// Driver
// ---------------------------------------------------------------------------
extern "C" void kernel_launch(void* const* d_in, const int* in_sizes, int n_in,
                              void* d_out, int out_size, void* d_ws, size_t ws_size,
                              hipStream_t stream) {
  const float* x     = (const float*)d_in[0];
  const int*   eidx  = (const int*)d_in[1];     // [2][E]
  const int*   batch = (const int*)d_in[2];     // [N]
  const float* W0    = (const float*)d_in[3];
  const float* b0    = (const float*)d_in[4];
  const float* Whid  = (const float*)d_in[5];   // [2][128][128]
  const float* bhid  = (const float*)d_in[6];   // [2][128]
  const float* Wout  = (const float*)d_in[7];   // [256]
  const float* bout  = (const float*)d_in[8];   // [1]
  float* out = (float*)d_out;

  const int N = in_sizes[0] / NF;
  const int E = in_sizes[1] / 2;
  const int G = out_size;

  const int* erow = eidx;
  const int* ecol = eidx + E;

  // workspace layout (256B aligned)
  size_t off = 0;
  auto alloc = [&](size_t bytes) -> void* {
    void* p = (char*)d_ws + off;
    off += (bytes + 255) & ~(size_t)255;
    return p;
  };
  int*      cnt    = (int*)alloc((size_t)N * 4);
  float*    dinv   = (float*)alloc((size_t)N * 4);
  int*      offs   = (int*)alloc((size_t)N * 4);
  int*      cursor = (int*)alloc((size_t)N * 4);
  int*      total  = (int*)alloc(16);
  int2*     csr    = (int2*)alloc((size_t)E * 8);
  _Float16* tmp    = (_Float16*)alloc((size_t)N * NF * 2);
  float*    h      = (float*)alloc((size_t)N * NF * 4);
  (void)ws_size;

  (void)hipMemsetAsync(cnt, 0, (size_t)N * 4, stream);
  (void)hipMemsetAsync(total, 0, 16, stream);

  int gE = (E + 255) / 256;
  int gN = (N + 255) / 256;

  k_count<<<gE, 256, 0, stream>>>(ecol, cnt, E);
  k_nodeinit<<<gN, 256, 0, stream>>>(cnt, dinv, offs, cursor, total, N);
  k_fill<<<gE, 256, 0, stream>>>(erow, ecol, dinv, cursor, csr, E);

  const int gemmGrid = (N + BM - 1) / BM;
  const int aggGrid = (N + 7) / 8;          // 8 nodes (half-waves) per 256-thr block

  // layer 0: x -> tmp -> h
  k_gemm<<<gemmGrid, 256, 0, stream>>>(x, W0, tmp, N);
  k_agg<<<aggGrid, 256, 0, stream>>>(tmp, offs, cursor, csr, dinv, b0, h, N);
  // layer 1
  k_gemm<<<gemmGrid, 256, 0, stream>>>(h, Whid, tmp, N);
  k_agg<<<aggGrid, 256, 0, stream>>>(tmp, offs, cursor, csr, dinv, bhid, h, N);
  // layer 2
  k_gemm<<<gemmGrid, 256, 0, stream>>>(h, Whid + 128 * 128, tmp, N);
  k_agg<<<aggGrid, 256, 0, stream>>>(tmp, offs, cursor, csr, dinv, bhid + NF, h, N);

  // pooling + head
  k_pool<<<G, 512, 0, stream>>>(h, batch, Wout, bout, out, N);
}